// Round 2
// baseline (2361.691 us; speedup 1.0000x reference)
//
#include <hip/hip_runtime.h>
#include <hip/hip_bf16.h>

#define N_NODES 100000
#define N_EDGES 600000
#define DFEAT 128
#define DOUT 256

typedef __attribute__((ext_vector_type(8))) short bf16x8;
typedef __attribute__((ext_vector_type(4))) float floatx4;

__device__ __forceinline__ short f32_to_bfbits(float f) {
    __hip_bfloat16 h = __float2bfloat16(f);
    return *reinterpret_cast<short*>(&h);
}

// ---------------------------------------------------------------------------
// 1) Transpose weight f32[256][256] -> Wt bf16[n][k] so MFMA B-frags are
//    contiguous 16B loads.
// ---------------------------------------------------------------------------
__global__ void transpose_w_kernel(const float* __restrict__ w,
                                   __hip_bfloat16* __restrict__ wt) {
    int n = blockIdx.x;      // 0..255 (output col)
    int k = threadIdx.x;     // 0..255 (input row)
    wt[(size_t)n * DOUT + k] = __float2bfloat16(w[(size_t)k * DOUT + n]);
}

// ---------------------------------------------------------------------------
// 2) Scatter-sum: 16 threads per edge, 8 features per thread.
//    sums[row][:] += nf[col][:] (fp32 atomics), counts[row] += 1.
// ---------------------------------------------------------------------------
__global__ void scatter_kernel(const float* __restrict__ nf,
                               const int* __restrict__ ei,
                               float* __restrict__ sums,
                               float* __restrict__ counts) {
    int tid  = blockIdx.x * blockDim.x + threadIdx.x;
    int e    = tid >> 4;
    int lane = tid & 15;
    if (e >= N_EDGES) return;
    int r = ei[e];
    int c = ei[N_EDGES + e];
    if (r == c) return;   // self-loop removed

    const float4* p = reinterpret_cast<const float4*>(nf + (size_t)c * DFEAT + lane * 8);
    float4 v0 = p[0];
    float4 v1 = p[1];

    float* dst = sums + (size_t)r * DFEAT + lane * 8;
    atomicAdd(dst + 0, v0.x);
    atomicAdd(dst + 1, v0.y);
    atomicAdd(dst + 2, v0.z);
    atomicAdd(dst + 3, v0.w);
    atomicAdd(dst + 4, v1.x);
    atomicAdd(dst + 5, v1.y);
    atomicAdd(dst + 6, v1.z);
    atomicAdd(dst + 7, v1.w);
    if (lane == 0) atomicAdd(counts + r, 1.0f);
}

// ---------------------------------------------------------------------------
// 3) Fused: X = [sums/max(cnt,1), nf] (built in-register as bf16 A-frags),
//    O = X @ W + bias, L2-normalize rows, store f32.
//    Wave computes 16 rows x 256 cols via 16x16x32 bf16 MFMA.
//    A-frag: A[m=lane&15][k=quad*8+j] ; C/D: col=lane&15, row=quad*4+reg.
// ---------------------------------------------------------------------------
__global__ void __launch_bounds__(256)
gemm_norm_kernel(const float* __restrict__ sums,
                 const float* __restrict__ counts,
                 const float* __restrict__ nf,
                 const __hip_bfloat16* __restrict__ wt,
                 const float* __restrict__ bias,
                 float* __restrict__ out) {
    int wave = threadIdx.x >> 6;   // 0..3
    int lane = threadIdx.x & 63;
    int l15  = lane & 15;
    int quad = lane >> 4;          // 0..3

    int rowBase = blockIdx.x * 64 + wave * 16;
    int arow = rowBase + l15;
    if (arow >= N_NODES) arow = N_NODES - 1;   // clamp loads; stores guarded

    float cnt  = counts[arow];
    float invc = 1.0f / fmaxf(cnt, 1.0f);

    // Build all 8 A k-tiles (K=256 = 8 * 32).
    bf16x8 afrag[8];
    const float* srow = sums + (size_t)arow * DFEAT;
    #pragma unroll
    for (int kt = 0; kt < 4; ++kt) {          // k in [0,128): mean part
        const float4* p = reinterpret_cast<const float4*>(srow + kt * 32 + quad * 8);
        float4 x0 = p[0];
        float4 x1 = p[1];
        bf16x8 a;
        a[0] = f32_to_bfbits(x0.x * invc);
        a[1] = f32_to_bfbits(x0.y * invc);
        a[2] = f32_to_bfbits(x0.z * invc);
        a[3] = f32_to_bfbits(x0.w * invc);
        a[4] = f32_to_bfbits(x1.x * invc);
        a[5] = f32_to_bfbits(x1.y * invc);
        a[6] = f32_to_bfbits(x1.z * invc);
        a[7] = f32_to_bfbits(x1.w * invc);
        afrag[kt] = a;
    }
    const float* nrow = nf + (size_t)arow * DFEAT;
    #pragma unroll
    for (int kt = 0; kt < 4; ++kt) {          // k in [128,256): raw features
        const float4* p = reinterpret_cast<const float4*>(nrow + kt * 32 + quad * 8);
        float4 x0 = p[0];
        float4 x1 = p[1];
        bf16x8 a;
        a[0] = f32_to_bfbits(x0.x);
        a[1] = f32_to_bfbits(x0.y);
        a[2] = f32_to_bfbits(x0.z);
        a[3] = f32_to_bfbits(x0.w);
        a[4] = f32_to_bfbits(x1.x);
        a[5] = f32_to_bfbits(x1.y);
        a[6] = f32_to_bfbits(x1.z);
        a[7] = f32_to_bfbits(x1.w);
        afrag[4 + kt] = a;
    }

    floatx4 acc[16];
    #pragma unroll
    for (int cb = 0; cb < 16; ++cb) acc[cb] = (floatx4){0.f, 0.f, 0.f, 0.f};

    #pragma unroll
    for (int kt = 0; kt < 8; ++kt) {
        bf16x8 a = afrag[kt];
        #pragma unroll
        for (int cb = 0; cb < 16; ++cb) {
            // B[k][n] = W[k][n] = Wt[n][k]; frag: n=l15, k = kt*32+quad*8+j
            const bf16x8 b = *reinterpret_cast<const bf16x8*>(
                wt + (size_t)(cb * 16 + l15) * DOUT + kt * 32 + quad * 8);
            acc[cb] = __builtin_amdgcn_mfma_f32_16x16x32_bf16(a, b, acc[cb], 0, 0, 0);
        }
    }

    // Epilogue: + bias, row L2 norm (rows quad*4+reg live in this quad's 16 lanes)
    float ss[4] = {0.f, 0.f, 0.f, 0.f};
    #pragma unroll
    for (int cb = 0; cb < 16; ++cb) {
        float bv = bias[cb * 16 + l15];
        #pragma unroll
        for (int rg = 0; rg < 4; ++rg) {
            float v = acc[cb][rg] + bv;
            acc[cb][rg] = v;
            ss[rg] += v * v;
        }
    }
    #pragma unroll
    for (int m = 1; m < 16; m <<= 1) {
        #pragma unroll
        for (int rg = 0; rg < 4; ++rg)
            ss[rg] += __shfl_xor(ss[rg], m, 64);
    }
    float inv[4];
    #pragma unroll
    for (int rg = 0; rg < 4; ++rg)
        inv[rg] = 1.0f / fmaxf(sqrtf(ss[rg]), 1e-12f);

    #pragma unroll
    for (int rg = 0; rg < 4; ++rg) {
        int r = rowBase + quad * 4 + rg;
        if (r >= N_NODES) continue;
        size_t base = (size_t)r * DOUT + l15;
        #pragma unroll
        for (int cb = 0; cb < 16; ++cb) {
            out[base + cb * 16] = acc[cb][rg] * inv[rg];
        }
    }
}

extern "C" void kernel_launch(void* const* d_in, const int* in_sizes, int n_in,
                              void* d_out, int out_size, void* d_ws, size_t ws_size,
                              hipStream_t stream) {
    const float* nf   = (const float*)d_in[0];
    const int*   ei   = (const int*)d_in[1];
    const float* w    = (const float*)d_in[2];
    const float* bias = (const float*)d_in[3];
    float* out = (float*)d_out;

    // Workspace layout:
    //   [0, 12.8M floats)       : sums   (100000 x 128 fp32)
    //   [12.8M, 12.9M floats)   : counts (100000 fp32)
    //   after                   : Wt     (256 x 256 bf16)
    float* sums   = (float*)d_ws;
    float* counts = sums + (size_t)N_NODES * DFEAT;
    __hip_bfloat16* wt = (__hip_bfloat16*)((char*)d_ws + (size_t)(N_NODES * DFEAT + N_NODES) * 4);

    hipMemsetAsync(d_ws, 0, (size_t)(N_NODES * DFEAT + N_NODES) * 4, stream);

    transpose_w_kernel<<<DOUT, DOUT, 0, stream>>>(w, wt);

    int scatter_blocks = (N_EDGES * 16) / 256;   // 37500
    scatter_kernel<<<scatter_blocks, 256, 0, stream>>>(nf, ei, sums, counts);

    int gemm_blocks = (N_NODES + 63) / 64;       // 1563
    gemm_norm_kernel<<<gemm_blocks, 256, 0, stream>>>(sums, counts, nf, wt, bias, out);
}

// Round 3
// 361.294 us; speedup vs baseline: 6.5368x; 6.5368x over previous
//
#include <hip/hip_runtime.h>
#include <hip/hip_bf16.h>

#define N_NODES 100000
#define N_EDGES 600000
#define DFEAT 128
#define DOUT 256
#define SCAN_B 256
#define N_SCAN_BLOCKS ((N_NODES + SCAN_B - 1) / SCAN_B)   // 391

typedef __attribute__((ext_vector_type(8))) short bf16x8;
typedef __attribute__((ext_vector_type(4))) float floatx4;

__device__ __forceinline__ short f32_to_bfbits(float f) {
    __hip_bfloat16 h = __float2bfloat16(f);
    return *reinterpret_cast<short*>(&h);
}

// ---------------------------------------------------------------------------
// Wt: f32[256][256] -> bf16 Wt[n][k] (contiguous 16B MFMA B-frags)
// ---------------------------------------------------------------------------
__global__ void transpose_w_kernel(const float* __restrict__ w,
                                   __hip_bfloat16* __restrict__ wt) {
    int n = blockIdx.x;
    int k = threadIdx.x;
    wt[(size_t)n * DOUT + k] = __float2bfloat16(w[(size_t)k * DOUT + n]);
}

// ---------------------------------------------------------------------------
// CSR build: degree histogram (int atomics, L2-resident counters)
// ---------------------------------------------------------------------------
__global__ void hist_kernel(const int* __restrict__ ei, int* __restrict__ deg) {
    int e = blockIdx.x * blockDim.x + threadIdx.x;
    if (e >= N_EDGES) return;
    int r = ei[e];
    int c = ei[N_EDGES + e];
    if (r != c) atomicAdd(&deg[r], 1);
}

// Exclusive scan, 3 kernels (block scan -> partials scan -> add back)
__global__ void scan_block_kernel(const int* __restrict__ deg,
                                  int* __restrict__ offsets,
                                  int* __restrict__ partials) {
    __shared__ int tmp[SCAN_B];
    int tid = threadIdx.x;
    int i = blockIdx.x * SCAN_B + tid;
    int v = (i < N_NODES) ? deg[i] : 0;
    int x = v;
    tmp[tid] = x;
    __syncthreads();
    #pragma unroll
    for (int off = 1; off < SCAN_B; off <<= 1) {
        int y = (tid >= off) ? tmp[tid - off] : 0;
        __syncthreads();
        x += y;
        tmp[tid] = x;
        __syncthreads();
    }
    if (i < N_NODES) offsets[i] = x - v;           // exclusive within block
    if (tid == SCAN_B - 1) partials[blockIdx.x] = x;  // block total
}

__global__ void scan_partials_kernel(int* __restrict__ partials) {
    __shared__ int tmp[512];
    int tid = threadIdx.x;   // 512 threads
    int v = (tid < N_SCAN_BLOCKS) ? partials[tid] : 0;
    int x = v;
    tmp[tid] = x;
    __syncthreads();
    #pragma unroll
    for (int off = 1; off < 512; off <<= 1) {
        int y = (tid >= off) ? tmp[tid - off] : 0;
        __syncthreads();
        x += y;
        tmp[tid] = x;
        __syncthreads();
    }
    if (tid < N_SCAN_BLOCKS) partials[tid] = x - v;   // exclusive
}

__global__ void scan_add_kernel(int* __restrict__ offsets,
                                const int* __restrict__ partials) {
    int i = blockIdx.x * SCAN_B + threadIdx.x;
    if (i < N_NODES) offsets[i] += partials[blockIdx.x];
}

// Bucket fill: 1 int atomic per valid edge
__global__ void fill_kernel(const int* __restrict__ ei,
                            const int* __restrict__ offsets,
                            int* __restrict__ cursor,
                            int* __restrict__ ebuf) {
    int e = blockIdx.x * blockDim.x + threadIdx.x;
    if (e >= N_EDGES) return;
    int r = ei[e];
    int c = ei[N_EDGES + e];
    if (r == c) return;
    int pos = atomicAdd(&cursor[r], 1);
    ebuf[offsets[r] + pos] = c;
}

// ---------------------------------------------------------------------------
// Gather + mean: 32 threads per row (float4/lane = 128 floats), register acc.
// ---------------------------------------------------------------------------
__global__ void __launch_bounds__(256)
gather_mean_kernel(const float* __restrict__ nf,
                   const int* __restrict__ deg,
                   const int* __restrict__ offsets,
                   const int* __restrict__ ebuf,
                   float* __restrict__ mean) {
    int row = blockIdx.x * 8 + (threadIdx.x >> 5);
    int l = threadIdx.x & 31;
    if (row >= N_NODES) return;
    int d = deg[row];
    int off = offsets[row];
    float4 acc = make_float4(0.f, 0.f, 0.f, 0.f);
    int j = 0;
    for (; j + 1 < d; j += 2) {            // 2-way to keep 2 loads in flight
        int c0 = ebuf[off + j];
        int c1 = ebuf[off + j + 1];
        float4 v0 = *reinterpret_cast<const float4*>(nf + (size_t)c0 * DFEAT + l * 4);
        float4 v1 = *reinterpret_cast<const float4*>(nf + (size_t)c1 * DFEAT + l * 4);
        acc.x += v0.x + v1.x; acc.y += v0.y + v1.y;
        acc.z += v0.z + v1.z; acc.w += v0.w + v1.w;
    }
    if (j < d) {
        int c0 = ebuf[off + j];
        float4 v0 = *reinterpret_cast<const float4*>(nf + (size_t)c0 * DFEAT + l * 4);
        acc.x += v0.x; acc.y += v0.y; acc.z += v0.z; acc.w += v0.w;
    }
    float inv = 1.0f / fmaxf((float)d, 1.0f);
    *reinterpret_cast<float4*>(mean + (size_t)row * DFEAT + l * 4) =
        make_float4(acc.x * inv, acc.y * inv, acc.z * inv, acc.w * inv);
}

// ---------------------------------------------------------------------------
// Fallback scatter (only if ws too small for CSR): fp32 atomics
// ---------------------------------------------------------------------------
__global__ void scatter_kernel(const float* __restrict__ nf,
                               const int* __restrict__ ei,
                               float* __restrict__ sums,
                               float* __restrict__ counts) {
    int tid = blockIdx.x * blockDim.x + threadIdx.x;
    int e = tid >> 4;
    int lane = tid & 15;
    if (e >= N_EDGES) return;
    int r = ei[e];
    int c = ei[N_EDGES + e];
    if (r == c) return;
    const float4* p = reinterpret_cast<const float4*>(nf + (size_t)c * DFEAT + lane * 8);
    float4 v0 = p[0], v1 = p[1];
    float* dst = sums + (size_t)r * DFEAT + lane * 8;
    atomicAdd(dst + 0, v0.x); atomicAdd(dst + 1, v0.y);
    atomicAdd(dst + 2, v0.z); atomicAdd(dst + 3, v0.w);
    atomicAdd(dst + 4, v1.x); atomicAdd(dst + 5, v1.y);
    atomicAdd(dst + 6, v1.z); atomicAdd(dst + 7, v1.w);
    if (lane == 0) atomicAdd(counts + r, 1.0f);
}

__global__ void finalize_mean_kernel(float* __restrict__ sums,
                                     const float* __restrict__ counts) {
    int i = blockIdx.x * blockDim.x + threadIdx.x;   // one float4 per thread
    if (i >= N_NODES * (DFEAT / 4)) return;
    int row = i / (DFEAT / 4);
    float inv = 1.0f / fmaxf(counts[row], 1.0f);
    float4* p = reinterpret_cast<float4*>(sums) + i;
    float4 v = *p;
    *p = make_float4(v.x * inv, v.y * inv, v.z * inv, v.w * inv);
}

// ---------------------------------------------------------------------------
// Fused GEMM: X = [mean, nf] (bf16 A-frags built in-register),
// O = X@W + bias, L2-normalize, store f32.
// A-frag: A[m=lane&15][k=quad*8+j] ; C/D: col=lane&15, row=quad*4+reg.
// ---------------------------------------------------------------------------
__global__ void __launch_bounds__(256)
gemm_norm_kernel(const float* __restrict__ mean,
                 const float* __restrict__ nf,
                 const __hip_bfloat16* __restrict__ wt,
                 const float* __restrict__ bias,
                 float* __restrict__ out) {
    int wave = threadIdx.x >> 6;
    int lane = threadIdx.x & 63;
    int l15 = lane & 15;
    int quad = lane >> 4;

    int rowBase = blockIdx.x * 64 + wave * 16;
    int arow = rowBase + l15;
    if (arow >= N_NODES) arow = N_NODES - 1;

    bf16x8 afrag[8];
    const float* srow = mean + (size_t)arow * DFEAT;
    const float* nrow = nf + (size_t)arow * DFEAT;
    #pragma unroll
    for (int kt = 0; kt < 4; ++kt) {
        const float4* p = reinterpret_cast<const float4*>(srow + kt * 32 + quad * 8);
        float4 x0 = p[0], x1 = p[1];
        bf16x8 a;
        a[0] = f32_to_bfbits(x0.x); a[1] = f32_to_bfbits(x0.y);
        a[2] = f32_to_bfbits(x0.z); a[3] = f32_to_bfbits(x0.w);
        a[4] = f32_to_bfbits(x1.x); a[5] = f32_to_bfbits(x1.y);
        a[6] = f32_to_bfbits(x1.z); a[7] = f32_to_bfbits(x1.w);
        afrag[kt] = a;
    }
    #pragma unroll
    for (int kt = 0; kt < 4; ++kt) {
        const float4* p = reinterpret_cast<const float4*>(nrow + kt * 32 + quad * 8);
        float4 x0 = p[0], x1 = p[1];
        bf16x8 a;
        a[0] = f32_to_bfbits(x0.x); a[1] = f32_to_bfbits(x0.y);
        a[2] = f32_to_bfbits(x0.z); a[3] = f32_to_bfbits(x0.w);
        a[4] = f32_to_bfbits(x1.x); a[5] = f32_to_bfbits(x1.y);
        a[6] = f32_to_bfbits(x1.z); a[7] = f32_to_bfbits(x1.w);
        afrag[4 + kt] = a;
    }

    floatx4 acc[16];
    #pragma unroll
    for (int cb = 0; cb < 16; ++cb) acc[cb] = (floatx4){0.f, 0.f, 0.f, 0.f};

    #pragma unroll
    for (int kt = 0; kt < 8; ++kt) {
        bf16x8 a = afrag[kt];
        #pragma unroll
        for (int cb = 0; cb < 16; ++cb) {
            const bf16x8 b = *reinterpret_cast<const bf16x8*>(
                wt + (size_t)(cb * 16 + l15) * DOUT + kt * 32 + quad * 8);
            acc[cb] = __builtin_amdgcn_mfma_f32_16x16x32_bf16(a, b, acc[cb], 0, 0, 0);
        }
    }

    float ss[4] = {0.f, 0.f, 0.f, 0.f};
    #pragma unroll
    for (int cb = 0; cb < 16; ++cb) {
        float bv = bias[cb * 16 + l15];
        #pragma unroll
        for (int rg = 0; rg < 4; ++rg) {
            float v = acc[cb][rg] + bv;
            acc[cb][rg] = v;
            ss[rg] += v * v;
        }
    }
    #pragma unroll
    for (int m = 1; m < 16; m <<= 1) {
        #pragma unroll
        for (int rg = 0; rg < 4; ++rg) ss[rg] += __shfl_xor(ss[rg], m, 64);
    }
    float inv[4];
    #pragma unroll
    for (int rg = 0; rg < 4; ++rg)
        inv[rg] = 1.0f / fmaxf(sqrtf(ss[rg]), 1e-12f);

    #pragma unroll
    for (int rg = 0; rg < 4; ++rg) {
        int r = rowBase + quad * 4 + rg;
        if (r >= N_NODES) continue;
        size_t base = (size_t)r * DOUT + l15;
        #pragma unroll
        for (int cb = 0; cb < 16; ++cb) out[base + cb * 16] = acc[cb][rg] * inv[rg];
    }
}

extern "C" void kernel_launch(void* const* d_in, const int* in_sizes, int n_in,
                              void* d_out, int out_size, void* d_ws, size_t ws_size,
                              hipStream_t stream) {
    const float* nf   = (const float*)d_in[0];
    const int*   ei   = (const int*)d_in[1];
    const float* w    = (const float*)d_in[2];
    const float* bias = (const float*)d_in[3];
    float* out = (float*)d_out;

    // Workspace layout (CSR path, ~55 MB):
    //   mean     : 100000*128 f32      (51.2 MB)
    //   deg      : 100000 int
    //   cursor   : 100000 int          (adjacent to deg -> one memset)
    //   offsets  : 100000 int
    //   partials : 512 int
    //   ebuf     : 600000 int
    //   wt       : 256*256 bf16
    float* mean   = (float*)d_ws;
    int* deg      = (int*)(mean + (size_t)N_NODES * DFEAT);
    int* cursor   = deg + N_NODES;
    int* offsets  = cursor + N_NODES;
    int* partials = offsets + N_NODES;
    int* ebuf     = partials + 512;
    __hip_bfloat16* wt = (__hip_bfloat16*)(ebuf + N_EDGES);
    size_t need = (size_t)((char*)(wt + DOUT * DOUT) - (char*)d_ws);

    transpose_w_kernel<<<DOUT, DOUT, 0, stream>>>(w, wt);

    if (ws_size >= need) {
        // CSR path: no fp32 atomics
        hipMemsetAsync(deg, 0, 2 * N_NODES * sizeof(int), stream);  // deg + cursor
        int eb = (N_EDGES + 255) / 256;
        hist_kernel<<<eb, 256, 0, stream>>>(ei, deg);
        scan_block_kernel<<<N_SCAN_BLOCKS, SCAN_B, 0, stream>>>(deg, offsets, partials);
        scan_partials_kernel<<<1, 512, 0, stream>>>(partials);
        scan_add_kernel<<<N_SCAN_BLOCKS, SCAN_B, 0, stream>>>(offsets, partials);
        fill_kernel<<<eb, 256, 0, stream>>>(ei, offsets, cursor, ebuf);
        gather_mean_kernel<<<N_NODES / 8, 256, 0, stream>>>(nf, deg, offsets, ebuf, mean);
    } else {
        // Fallback: atomic scatter (R2 behavior)
        float* counts = (float*)deg;
        hipMemsetAsync(d_ws, 0, (size_t)(N_NODES * DFEAT + N_NODES) * 4, stream);
        int sb = (N_EDGES * 16) / 256;
        scatter_kernel<<<sb, 256, 0, stream>>>(nf, ei, mean, counts);
        finalize_mean_kernel<<<(N_NODES * (DFEAT / 4) + 255) / 256, 256, 0, stream>>>(mean, counts);
    }

    int gemm_blocks = (N_NODES + 63) / 64;
    gemm_norm_kernel<<<gemm_blocks, 256, 0, stream>>>(mean, nf, wt, bias, out);
}